// Round 5
// baseline (1225.237 us; speedup 1.0000x reference)
//
#include <hip/hip_runtime.h>
#include <hip/hip_bf16.h>
#include <math.h>

#define N_BATCH 2048
#define T_STEPS 50
#define NCODES  40
#define MH      526
#define AUXD    10
#define WLROWS  536    // MH + AUXD
#define KPAD    544    // WLROWS padded to 17*32
#define E_DIM   256
#define G_DIM   1024   // 4*E
#define BM      16     // batch rows per recurrence block
#define TCHUNK  10     // time steps per chunk (5 chunks)
#define MBLK    32     // (n,t) rows per fused block

typedef __attribute__((ext_vector_type(8))) short short8;   // 8 bf16 = 4 VGPR
typedef __attribute__((ext_vector_type(4))) short short4v;  // 4 bf16 = 2 VGPR
typedef __attribute__((ext_vector_type(4))) float f32x4;

__device__ __forceinline__ short f2bf(float f) {
    __hip_bfloat16 h = __float2bfloat16(f);
    return *reinterpret_cast<short*>(&h);
}
__device__ __forceinline__ float bf2f(unsigned short u) {
    return __uint_as_float(((unsigned int)u) << 16);
}
__device__ __forceinline__ float sigf(float x) {
    return 1.f / (1.f + __expf(-x));
}
__device__ __forceinline__ float tanhfast(float x) {
    return 2.f / (1.f + __expf(-2.f * x)) - 1.f;
}

// ---------------------------------------------------------------------------
// Prep A: Wlt[n][k] bf16 = W_lin[k][n] (k<536, zero-padded to 544)
// ---------------------------------------------------------------------------
__global__ __launch_bounds__(256) void k_prepwl(
    const float* __restrict__ W_lin, short* __restrict__ Wlt)
{
    const int tid = threadIdx.x;
    const int kt = blockIdx.x >> 2;      // 0..16
    const int nt = blockIdx.x & 3;       // 0..3
    const int k0 = kt * 32, n0 = nt * 64;

    __shared__ float tile[32][65];

    #pragma unroll
    for (int it = 0; it < 8; ++it) {
        const int idx = tid + it * 256;
        const int kk = idx >> 6, nn = idx & 63;
        const int k = k0 + kk;
        tile[kk][nn] = (k < WLROWS) ? W_lin[(size_t)k * E_DIM + n0 + nn] : 0.f;
    }
    __syncthreads();

    const int n  = tid >> 2;
    const int kg = tid & 3;
    int4 v;
    int* vi = (int*)&v;
    #pragma unroll
    for (int j = 0; j < 4; ++j) {
        int lo = f2bf(tile[kg * 8 + 2 * j][n]) & 0xffff;
        int hi = f2bf(tile[kg * 8 + 2 * j + 1][n]) & 0xffff;
        vi[j] = lo | (hi << 16);
    }
    *(int4*)(Wlt + (size_t)(n0 + n) * KPAD + k0 + kg * 8) = v;
}

// ---------------------------------------------------------------------------
// Prep B: Wt[n][k] (bf16, k=0..511) = [K;R][k][n]
// ---------------------------------------------------------------------------
__global__ __launch_bounds__(256) void k_prep(
    const float* __restrict__ K, const float* __restrict__ R,
    short* __restrict__ Wt)
{
    const int tid = threadIdx.x;
    const int kt = blockIdx.x & 7;
    const int nt = blockIdx.x >> 3;
    const int k0 = kt * 64, n0 = nt * 64;

    __shared__ float tile[64][65];

    const int nloc_r = tid & 63;
    for (int kloc = tid >> 6; kloc < 64; kloc += 4) {
        const int k = k0 + kloc;
        float v = (k < 256) ? K[(size_t)k * G_DIM + n0 + nloc_r]
                            : R[(size_t)(k - 256) * G_DIM + n0 + nloc_r];
        tile[kloc][nloc_r] = v;
    }
    __syncthreads();

    const int nloc = tid >> 2;
    const int kc   = (tid & 3) * 16;
    int* dst = (int*)(Wt + (size_t)(n0 + nloc) * 512 + k0 + kc);
    #pragma unroll
    for (int j = 0; j < 8; ++j) {
        int lo = f2bf(tile[kc + 2 * j][nloc]) & 0xffff;
        int hi = f2bf(tile[kc + 2 * j + 1][nloc]) & 0xffff;
        dst[j] = lo | (hi << 16);
    }
}

// ---------------------------------------------------------------------------
// Fused embed + xz GEMM for one t-chunk, tl-major.
// Block = 32 consecutive n at fixed tl. Output written in k_rec fragment
// order: frag block idx = ((rg*TCHUNK+tl)*8 + w')*8 + f', 256 shorts each,
// lane writes short4 at +lane*4.
// ---------------------------------------------------------------------------
__global__ __launch_bounds__(512) void k_fused(
    const int* __restrict__ code, const float* __restrict__ aux,
    const short* __restrict__ Wlt, const float* __restrict__ b_lin,
    const short* __restrict__ Wt, short* __restrict__ xzp, int t0)
{
    const int tid  = threadIdx.x;
    const int w    = tid >> 6;
    const int lane = tid & 63;
    const int lr   = lane & 15;
    const int p    = lane >> 4;
    const int tl   = blockIdx.x >> 6;          // 0..TCHUNK-1
    const int n0   = (blockIdx.x & 63) * MBLK; // 32 consecutive batch rows
    const int t    = t0 + tl;

    __shared__ __align__(16) short oh[MBLK][552];
    __shared__ __align__(16) short xs[MBLK][264];

    // ---- zero one-hot ----
    for (int i = tid; i < (MBLK * 552) / 8; i += 512)
        ((int4*)&oh[0][0])[i] = (int4){0, 0, 0, 0};
    __syncthreads();

    // ---- scatter codes (presence; duplicates idempotent; drop c==0) ----
    for (int i = tid; i < MBLK * NCODES; i += 512) {
        const int r = i / NCODES;
        const int j = i - r * NCODES;
        const int c = code[((size_t)(n0 + r) * T_STEPS + t) * NCODES + j];
        if (c > 0) ((unsigned short*)&oh[0][0])[r * 552 + (c - 1)] = 0x3F80;
    }
    if (tid < MBLK * AUXD) {
        const int r = tid / AUXD;
        const int a = tid - r * AUXD;
        oh[r][MH + a] = f2bf(aux[((size_t)(n0 + r) * T_STEPS + t) * AUXD + a]);
    }
    __syncthreads();

    // ---- Phase 2: xs = relu(oh @ Wlt^T + b_lin), wave cols w*32.. ----
    {
        f32x4 acc[2][2];
        #pragma unroll
        for (int rb = 0; rb < 2; ++rb)
            #pragma unroll
            for (int cb = 0; cb < 2; ++cb)
                acc[rb][cb] = (f32x4){0.f, 0.f, 0.f, 0.f};

        for (int kk = 0; kk < 17; ++kk) {
            short8 a0 = *(const short8*)&oh[lr][kk * 32 + p * 8];
            short8 a1 = *(const short8*)&oh[16 + lr][kk * 32 + p * 8];
            #pragma unroll
            for (int cb = 0; cb < 2; ++cb) {
                short8 bf = *(const short8*)(Wlt +
                    (size_t)(w * 32 + cb * 16 + lr) * KPAD + kk * 32 + p * 8);
                acc[0][cb] = __builtin_amdgcn_mfma_f32_16x16x32_bf16(a0, bf, acc[0][cb], 0, 0, 0);
                acc[1][cb] = __builtin_amdgcn_mfma_f32_16x16x32_bf16(a1, bf, acc[1][cb], 0, 0, 0);
            }
        }
        float bias[2];
        #pragma unroll
        for (int cb = 0; cb < 2; ++cb) bias[cb] = b_lin[w * 32 + cb * 16 + lr];
        __syncthreads();
        #pragma unroll
        for (int rb = 0; rb < 2; ++rb)
            #pragma unroll
            for (int cb = 0; cb < 2; ++cb)
                #pragma unroll
                for (int rr = 0; rr < 4; ++rr)
                    xs[rb * 16 + p * 4 + rr][w * 32 + cb * 16 + lr] =
                        f2bf(fmaxf(acc[rb][cb][rr] + bias[cb], 0.f));
        __syncthreads();
    }

    // ---- Phase 3: xz = xs @ Wt_K^T, wave cols w*128.., frag-order out ----
    {
        f32x4 acc[2][8];
        #pragma unroll
        for (int rb = 0; rb < 2; ++rb)
            #pragma unroll
            for (int cb = 0; cb < 8; ++cb)
                acc[rb][cb] = (f32x4){0.f, 0.f, 0.f, 0.f};

        for (int kb = 0; kb < 8; ++kb) {
            short8 a0 = *(const short8*)&xs[lr][kb * 32 + p * 8];
            short8 a1 = *(const short8*)&xs[16 + lr][kb * 32 + p * 8];
            short8 bf[8];
            #pragma unroll
            for (int cb = 0; cb < 8; ++cb)
                bf[cb] = *(const short8*)(Wt +
                    (size_t)(w * 128 + cb * 16 + lr) * 512 + kb * 32 + p * 8);
            #pragma unroll
            for (int cb = 0; cb < 8; ++cb) {
                acc[0][cb] = __builtin_amdgcn_mfma_f32_16x16x32_bf16(a0, bf[cb], acc[0][cb], 0, 0, 0);
                acc[1][cb] = __builtin_amdgcn_mfma_f32_16x16x32_bf16(a1, bf[cb], acc[1][cb], 0, 0, 0);
            }
        }
        #pragma unroll
        for (int rb = 0; rb < 2; ++rb) {
            const int rg = (n0 >> 4) + rb;   // k_rec row-group
            #pragma unroll
            for (int cb = 0; cb < 8; ++cb) {
                const int wp = (w & 1) * 4 + (cb >> 1);
                const int fp = (cb & 1) * 4 + (w >> 1);
                short4v v;
                #pragma unroll
                for (int rr = 0; rr < 4; ++rr) v[rr] = f2bf(acc[rb][cb][rr]);
                *(short4v*)(xzp +
                    ((((size_t)rg * TCHUNK + tl) * 8 + wp) * 8 + fp) * 256 +
                    lane * 4) = v;
            }
        }
    }
}

// ---------------------------------------------------------------------------
// Recurrence, 1024 threads = 16 waves: (kh = k-half, wc = col-group).
// Each wave: 8 col-frags x 4 k-steps over its 128-wide k-half. kh=1 writes
// partial z to LDS; kh=0 adds, applies gates, updates h_s/creg.
// xz arrives pre-permuted in fragment order (coalesced short4 loads).
// ---------------------------------------------------------------------------
__global__ __launch_bounds__(1024) void k_rec(
    const short* __restrict__ xzp, const int* __restrict__ length,
    const short* __restrict__ Wt, const float* __restrict__ b,
    short* __restrict__ h_state, float* __restrict__ c_state,
    float* __restrict__ xlast, int t0)
{
    const int tid  = threadIdx.x;
    const int w16  = tid >> 6;           // 0..15
    const int wc   = w16 & 7;
    const int kh   = w16 >> 3;
    const int lane = tid & 63;
    const int lr   = lane & 15;
    const int p    = lane >> 4;
    const int r0   = blockIdx.x * BM;
    const int rg   = blockIdx.x;

    __shared__ __align__(16) short h_s[BM][264];
    __shared__ float zb[BM][1028];       // partial z from kh=1 (65.8 KB)
    __shared__ int s_len[BM];
    __shared__ int s_maxlen;

    if (tid < BM) s_len[tid] = length[r0 + tid];
    __syncthreads();
    if (tid == 0) {
        int m = 0;
        for (int r2 = 0; r2 < BM; ++r2) m = max(m, s_len[r2]);
        s_maxlen = m;
    }
    __syncthreads();
    const int mlen = s_maxlen;
    if (mlen <= t0) return;
    const int steps = min(TCHUNK, mlen - t0);

    const int ecol = wc * 32 + lr;

    float creg[8];
    if (t0 == 0) {
        for (int i = tid; i < BM * 264; i += 1024) (&h_s[0][0])[i] = 0;
        #pragma unroll
        for (int i = 0; i < 8; ++i) creg[i] = 0.f;
    } else {
        for (int i = tid; i < BM * E_DIM; i += 1024) {
            int r2 = i >> 8, e = i & 255;
            h_s[r2][e] = h_state[(size_t)(r0 + r2) * E_DIM + e];
        }
        #pragma unroll
        for (int eb = 0; eb < 2; ++eb)
            #pragma unroll
            for (int rr = 0; rr < 4; ++rr)
                creg[eb * 4 + rr] =
                    c_state[(size_t)(r0 + p * 4 + rr) * E_DIM + ecol + eb * 16];
    }
    __syncthreads();

    int len_r[4];
    #pragma unroll
    for (int rr = 0; rr < 4; ++rr) len_r[rr] = s_len[p * 4 + rr];

    float bias[8];
    #pragma unroll
    for (int eb = 0; eb < 2; ++eb)
        #pragma unroll
        for (int g = 0; g < 4; ++g)
            bias[eb * 4 + g] = b[g * 256 + ecol + eb * 16];

    // B base: R-half of Wt, own k-half
    const short* wb = Wt + (size_t)(wc * 32 + lr) * 512 + 256 + kh * 128 + p * 8;

    for (int tl = 0; tl < steps; ++tl) {
        const int t = t0 + tl;

        // a-frags (own k-half of h) from LDS
        short8 a[4];
        #pragma unroll
        for (int kk = 0; kk < 4; ++kk)
            a[kk] = *(const short8*)(&h_s[lr][kh * 128 + kk * 32 + p * 8]);

        // acc init: kh=0 from pre-permuted xz (coalesced), kh=1 zero
        f32x4 acc[8];
        if (kh == 0) {
            #pragma unroll
            for (int f = 0; f < 8; ++f) {
                short4v v = *(const short4v*)(xzp +
                    ((((size_t)rg * TCHUNK + tl) * 8 + wc) * 8 + f) * 256 +
                    lane * 4);
                #pragma unroll
                for (int rr = 0; rr < 4; ++rr)
                    acc[f][rr] = bf2f((unsigned short)v[rr]);
            }
        } else {
            #pragma unroll
            for (int f = 0; f < 8; ++f) acc[f] = (f32x4){0.f, 0.f, 0.f, 0.f};
        }

        // MFMA: 4 k-steps x 8 frags (single-buffered B loads)
        #pragma unroll
        for (int kk = 0; kk < 4; ++kk) {
            short8 bf[8];
            #pragma unroll
            for (int f = 0; f < 8; ++f) {
                const int eb = f >> 2, g = f & 3;
                bf[f] = *(const short8*)(wb +
                    (size_t)(g * 256 + eb * 16) * 512 + kk * 32);
            }
            #pragma unroll
            for (int f = 0; f < 8; ++f)
                acc[f] = __builtin_amdgcn_mfma_f32_16x16x32_bf16(
                    a[kk], bf[f], acc[f], 0, 0, 0);
        }

        // kh=1 publishes partials
        if (kh == 1) {
            #pragma unroll
            for (int f = 0; f < 8; ++f) {
                const int eb = f >> 2, g = f & 3;
                const int col = g * 256 + wc * 32 + eb * 16 + lr;
                #pragma unroll
                for (int rr = 0; rr < 4; ++rr)
                    zb[p * 4 + rr][col] = acc[f][rr];
            }
        }
        __syncthreads();

        if (kh == 0) {
            short hnew[8];
            float hout[8];
            #pragma unroll
            for (int eb = 0; eb < 2; ++eb) {
                #pragma unroll
                for (int rr = 0; rr < 4; ++rr) {
                    const int row = p * 4 + rr;
                    const int e   = ecol + eb * 16;
                    float zi = acc[eb * 4 + 0][rr] + zb[row][0 * 256 + e] + bias[eb * 4 + 0];
                    float zf = acc[eb * 4 + 1][rr] + zb[row][1 * 256 + e] + bias[eb * 4 + 1];
                    float zg = acc[eb * 4 + 2][rr] + zb[row][2 * 256 + e] + bias[eb * 4 + 2];
                    float zo = acc[eb * 4 + 3][rr] + zb[row][3 * 256 + e] + bias[eb * 4 + 3];
                    float ig = sigf(zi), fg = sigf(zf);
                    float gg = tanhfast(zg), og = sigf(zo);
                    float cc = fg * creg[eb * 4 + rr] + ig * gg;
                    float hh = og * tanhfast(cc);
                    creg[eb * 4 + rr] = cc;
                    hnew[eb * 4 + rr] = f2bf(hh);
                    hout[eb * 4 + rr] = hh;
                }
            }
            #pragma unroll
            for (int eb = 0; eb < 2; ++eb) {
                #pragma unroll
                for (int rr = 0; rr < 4; ++rr) {
                    const int m = p * 4 + rr;
                    const int e = ecol + eb * 16;
                    h_s[m][e] = hnew[eb * 4 + rr];
                    if (t == len_r[rr] - 1)
                        xlast[(size_t)(r0 + m) * E_DIM + e] = hout[eb * 4 + rr];
                }
            }
        }
        __syncthreads();
    }

    // ---- save state ----
    for (int i = tid; i < BM * E_DIM; i += 1024) {
        int r2 = i >> 8, e = i & 255;
        h_state[(size_t)(r0 + r2) * E_DIM + e] = h_s[r2][e];
    }
    if (kh == 0) {
        #pragma unroll
        for (int eb = 0; eb < 2; ++eb)
            #pragma unroll
            for (int rr = 0; rr < 4; ++rr)
                c_state[(size_t)(r0 + p * 4 + rr) * E_DIM + ecol + eb * 16] =
                    creg[eb * 4 + rr];
    }
}

// ---------------------------------------------------------------------------
// Head MLP + L2 normalize (unchanged).
// ---------------------------------------------------------------------------
__global__ __launch_bounds__(256) void k_head(
    const float* __restrict__ xlast,
    const float* __restrict__ W0, const float* __restrict__ b0,
    const float* __restrict__ W1, const float* __restrict__ b1,
    float* __restrict__ out)
{
    const int n = blockIdx.x;
    const int j = threadIdx.x;

    __shared__ __align__(16) float xsh[E_DIM];
    __shared__ __align__(16) float y0[E_DIM];
    __shared__ float part[4];

    xsh[j] = xlast[(size_t)n * E_DIM + j];
    __syncthreads();

    float acc = b0[j];
    for (int k4 = 0; k4 < E_DIM; k4 += 4) {
        float4 xv = *reinterpret_cast<const float4*>(&xsh[k4]);
        #pragma unroll
        for (int kk = 0; kk < 4; ++kk)
            acc += (&xv.x)[kk] * W0[(size_t)(k4 + kk) * E_DIM + j];
    }
    y0[j] = fmaxf(acc, 0.f);
    __syncthreads();

    acc = b1[j];
    for (int k4 = 0; k4 < E_DIM; k4 += 4) {
        float4 yv = *reinterpret_cast<const float4*>(&y0[k4]);
        #pragma unroll
        for (int kk = 0; kk < 4; ++kk)
            acc += (&yv.x)[kk] * W1[(size_t)(k4 + kk) * E_DIM + j];
    }

    float sq = acc * acc;
    #pragma unroll
    for (int off = 32; off > 0; off >>= 1)
        sq += __shfl_xor(sq, off, 64);
    if ((j & 63) == 0) part[j >> 6] = sq;
    __syncthreads();
    float total = part[0] + part[1] + part[2] + part[3];

    out[(size_t)n * E_DIM + j] = acc * rsqrtf(total);
}

// ---------------------------------------------------------------------------
extern "C" void kernel_launch(void* const* d_in, const int* in_sizes, int n_in,
                              void* d_out, int out_size, void* d_ws, size_t ws_size,
                              hipStream_t stream) {
    const int*   code   = (const int*)  d_in[0];
    const float* aux    = (const float*)d_in[1];
    const int*   length = (const int*)  d_in[2];
    // d_in[3] = is_training (ignored)
    const float* W_lin  = (const float*)d_in[4];
    const float* b_lin  = (const float*)d_in[5];
    const float* K      = (const float*)d_in[6];
    const float* R      = (const float*)d_in[7];
    const float* b      = (const float*)d_in[8];
    const float* W0     = (const float*)d_in[9];
    const float* b0     = (const float*)d_in[10];
    const float* W1     = (const float*)d_in[11];
    const float* b1     = (const float*)d_in[12];
    float* out = (float*)d_out;

    // workspace layout (bytes, 16B aligned); total ~48.5 MB
    char* ws = (char*)d_ws;
    short* Wt      = (short*)(ws + 0);            //  1,048,576
    short* Wlt     = (short*)(ws + 1048576);      //    278,528
    float* xlast   = (float*)(ws + 1327104);      //  2,097,152
    short* h_state = (short*)(ws + 3424256);      //  1,048,576
    float* c_state = (float*)(ws + 4472832);      //  2,097,152
    short* xzp     = (short*)(ws + 6569984);      // 41,943,040

    k_prepwl<<<68,  256, 0, stream>>>(W_lin, Wlt);
    k_prep  <<<128, 256, 0, stream>>>(K, R, Wt);

    for (int c = 0; c < T_STEPS / TCHUNK; ++c) {
        const int t0 = c * TCHUNK;
        k_fused<<<64 * TCHUNK, 512, 0, stream>>>(
            code, aux, Wlt, b_lin, Wt, xzp, t0);
        k_rec<<<N_BATCH / BM, 1024, 0, stream>>>(xzp, length, Wt, b,
                                                 h_state, c_state, xlast, t0);
    }

    k_head<<<N_BATCH, 256, 0, stream>>>(xlast, W0, b0, W1, b1, out);
}